// Round 9
// baseline (348.950 us; speedup 1.0000x reference)
//
#include <hip/hip_runtime.h>

#define RTOT 12960      // 4 * 3240 rows
#define PAIRS 3240
#define NB_VAR 81
#define HID 256
#define EPS 1e-5f
#define NBLK 810        // 810 x 16 rows = 12960; <= 4*256 co-resident at launch_bounds(256,4)
#define NTHR 256
#define RPB 16          // rows per block

using bf8   = __attribute__((ext_vector_type(8))) short;
using f32x4 = __attribute__((ext_vector_type(4))) float;

__device__ inline ushort f2bf(float f) {
    union { float f; unsigned u; } c; c.f = f;
    unsigned u = c.u + 0x7fffu + ((c.u >> 16) & 1u);
    return (ushort)(u >> 16);
}
__device__ inline float bf2f(ushort h) {
    union { unsigned u; float f; } c; c.u = (unsigned)h << 16;
    return c.f;
}
__device__ inline unsigned pk2(float a, float b) {
    return (unsigned)f2bf(a) | ((unsigned)f2bf(b) << 16);
}
__device__ inline int2 pair_of(int p) {
    int i = (int)((161.0 - sqrt(25921.0 - 8.0 * (double)p)) * 0.5);
    if (i < 0) i = 0;
    while ((161 * (i + 1) - (i + 1) * (i + 1)) / 2 <= p) i++;
    while ((161 * i - i * i) / 2 > p) i--;
    int j = i + 1 + (p - (161 * i - i * i) / 2);
    return make_int2(i, j);
}

struct KP {
    const float *x, *w_in, *b_in, *g1, *beta1, *w1, *bias1, *g2, *beta2,
                *w2, *bias2, *fg, *fbeta, *w_out, *b_out;
    float *out;
    ushort *buf0, *buf1, *buf2, *pw;
    float *stats;   // 5 layers x 4 copies x 512
    int   *c;       // sync counters (memset 0 each launch)
};

// counter-only grid sync; fence pair only for the one-time weight publish
__device__ __forceinline__ void syncg(int* c, bool fence) {
    __syncthreads();
    if (threadIdx.x == 0) {
        if (fence) __threadfence();
        __hip_atomic_fetch_add(c, 1, __ATOMIC_RELAXED, __HIP_MEMORY_SCOPE_AGENT);
        while (__hip_atomic_load(c, __ATOMIC_RELAXED, __HIP_MEMORY_SCOPE_AGENT) < NBLK)
            __builtin_amdgcn_s_sleep(2);
        if (fence) __threadfence();
    }
    __syncthreads();
}

// BN coefficients from 4-way-split finalized stats (agent-scope loads bypass L1)
__device__ __forceinline__ void coeffs4(float* st, const float* g, const float* beta,
                                        float* sS, float* sT) {
    int tid = threadIdx.x;
    float s = 0.f, q = 0.f;
#pragma unroll
    for (int cp = 0; cp < 4; cp++) {
        s += __hip_atomic_load(st + cp * 512 + tid,       __ATOMIC_RELAXED, __HIP_MEMORY_SCOPE_AGENT);
        q += __hip_atomic_load(st + cp * 512 + 256 + tid, __ATOMIC_RELAXED, __HIP_MEMORY_SCOPE_AGENT);
    }
    float m = s * (1.f / RTOT);
    float v = q * (1.f / RTOT) - m * m;
    float sc = g[tid] * rsqrtf(v + EPS);
    sS[tid] = sc;
    sT[tid] = fmaf(-m, sc, beta[tid]);
    __syncthreads();
}

// A-fragment: 8 bf16 from own row, BN+ReLU in registers, repack bf16
__device__ __forceinline__ bf8 ldA(const ushort* xr, int kst,
                                   const float* sS, const float* sT) {
    float4 s0 = *(const float4*)&sS[kst], s1 = *(const float4*)&sS[kst + 4];
    float4 t0 = *(const float4*)&sT[kst], t1 = *(const float4*)&sT[kst + 4];
    ushort xv[8];
    *(uint4*)xv = *(const uint4*)(xr + kst);
    unsigned pk[4];
    pk[0] = pk2(fmaxf(fmaf(bf2f(xv[0]), s0.x, t0.x), 0.f),
                fmaxf(fmaf(bf2f(xv[1]), s0.y, t0.y), 0.f));
    pk[1] = pk2(fmaxf(fmaf(bf2f(xv[2]), s0.z, t0.z), 0.f),
                fmaxf(fmaf(bf2f(xv[3]), s0.w, t0.w), 0.f));
    pk[2] = pk2(fmaxf(fmaf(bf2f(xv[4]), s1.x, t1.x), 0.f),
                fmaxf(fmaf(bf2f(xv[5]), s1.y, t1.y), 0.f));
    pk[3] = pk2(fmaxf(fmaf(bf2f(xv[6]), s1.z, t1.z), 0.f),
                fmaxf(fmaf(bf2f(xv[7]), s1.w, t1.w), 0.f));
    return *(bf8*)pk;
}

// one 256->256 layer for this block's 16 rows; B from packed-global (coalesced); no barriers
__device__ __forceinline__ void layer16(const ushort* __restrict__ X,
        const ushort* __restrict__ PW, const float* __restrict__ bias,
        const ushort* __restrict__ res, ushort* __restrict__ Y,
        float* __restrict__ stout, const float* sS, const float* sT, int R0) {
    int tid = threadIdx.x, lane = tid & 63, wid = tid >> 6;
    int r16 = lane & 15, kq = lane >> 4;
    const ushort* xr = X + (size_t)(R0 + r16) * HID;
    const ushort* pb = PW + ((size_t)wid << 14) + lane * 8;   // cg = wid

    f32x4 acc[4] = {};
#pragma unroll
    for (int kk = 0; kk < 8; kk++) {
        int kst = kk * 32 + kq * 8;
        bf8 af = ldA(xr, kst, sS, sT);
        const ushort* pk = pb + (kk << 11);
        bf8 b0 = *(const bf8*)(pk + 0 * 512);
        bf8 b1 = *(const bf8*)(pk + 1 * 512);
        bf8 b2 = *(const bf8*)(pk + 2 * 512);
        bf8 b3 = *(const bf8*)(pk + 3 * 512);
        acc[0] = __builtin_amdgcn_mfma_f32_16x16x32_bf16(af, b0, acc[0], 0, 0, 0);
        acc[1] = __builtin_amdgcn_mfma_f32_16x16x32_bf16(af, b1, acc[1], 0, 0, 0);
        acc[2] = __builtin_amdgcn_mfma_f32_16x16x32_bf16(af, b2, acc[2], 0, 0, 0);
        acc[3] = __builtin_amdgcn_mfma_f32_16x16x32_bf16(af, b3, acc[3], 0, 0, 0);
    }

#pragma unroll
    for (int n = 0; n < 4; n++) {
        int col = wid * 64 + n * 16 + r16;
        float bv = bias[col];
        float cs = 0.f, cq = 0.f;
#pragma unroll
        for (int i = 0; i < 4; i++) {
            int r = R0 + kq * 4 + i;
            float v = acc[n][i] + bv;
            if (res) v += bf2f(res[(size_t)r * HID + col]);
            Y[(size_t)r * HID + col] = f2bf(v);
            cs += v; cq += v * v;
        }
        cs += __shfl_xor(cs, 16); cq += __shfl_xor(cq, 16);
        cs += __shfl_xor(cs, 32); cq += __shfl_xor(cq, 32);
        if (lane < 16) {
            atomicAdd(&stout[wid * 64 + n * 16 + lane], cs);
            atomicAdd(&stout[256 + wid * 64 + n * 16 + lane], cq);
        }
    }
}

__global__ __launch_bounds__(NTHR, 4) void fused(KP p) {
    __shared__ float sS[HID], sT[HID];
    __shared__ float feat[RPB][4];
    __shared__ int2 pairs_s[RPB];

    int tid = threadIdx.x;
    int b = blockIdx.x;
    int R0 = b * RPB;
    int gtid = b * NTHR + tid;
    float* st0 = p.stats + (b & 3) * 512;

    // ---- phase 0a: pack weights into MFMA fragment order (coalesced wave reads later) ----
    // mid: idx = ((L*4+cg)*8+kk)*4+n)*512 + lane*8 + e ; src W_L[col][k]
    for (int i = gtid; i < 262144 + 24576; i += NBLK * NTHR) {
        ushort val;
        if (i < 262144) {
            int L = i >> 16, r = i & 65535;
            int cg = r >> 14, r2 = r & 16383;
            int kk = r2 >> 11, r3 = r2 & 2047;
            int n = r3 >> 9, r4 = r3 & 511;
            int lane = r4 >> 3, e = r4 & 7;
            int col = cg * 64 + n * 16 + (lane & 15);
            int k = kk * 32 + (lane >> 4) * 8 + e;
            const float* Ws = (L == 0) ? p.w1 : (L == 1) ? p.w2
                           : (L == 2) ? p.w1 + 65536 : p.w2 + 65536;
            val = f2bf(Ws[col * HID + k]);
        } else {
            int j = i - 262144;
            int f = j >> 12, r2 = j & 4095;
            int kk = r2 >> 9, r3 = r2 & 511;
            int lane = r3 >> 3, e = r3 & 7;
            int col = f * 16 + (lane & 15);
            int k = kk * 32 + (lane >> 4) * 8 + e;
            val = (col < 81) ? f2bf(p.w_out[col * HID + k]) : (ushort)0;
        }
        p.pw[i] = val;
    }
    // ---- phase 0b: zero diagonal blocks of out ----
    for (int i = gtid; i < 4 * NB_VAR * 81; i += NBLK * NTHR) {
        int bb = i / (NB_VAR * 81);
        int rem = i - bb * (NB_VAR * 81);
        int ii = rem / 81, t = rem - ii * 81;
        p.out[((size_t)(bb * NB_VAR + ii) * NB_VAR + ii) * 81 + t] = 0.f;
    }
    // ---- phase 0c: input projection for own 16 rows + stats0 ----
    if (tid < RPB) {
        int r = R0 + tid;
        int bb = r / PAIRS, pp = r - bb * PAIRS;
        int2 ij = pair_of(pp);
        pairs_s[tid] = ij;
        const float* xb = p.x + bb * NB_VAR * 2;
        feat[tid][0] = xb[ij.x * 2 + 0];
        feat[tid][1] = xb[ij.x * 2 + 1];
        feat[tid][2] = xb[ij.y * 2 + 0];
        feat[tid][3] = xb[ij.y * 2 + 1];
    }
    __syncthreads();
    {
        float4 w = ((const float4*)p.w_in)[tid];
        float bi = p.b_in[tid];
        float s = 0.f, s2 = 0.f;
#pragma unroll
        for (int t = 0; t < RPB; t++) {
            float v = fmaf(feat[t][0], w.x, fmaf(feat[t][1], w.y,
                      fmaf(feat[t][2], w.z, fmaf(feat[t][3], w.w, bi))));
            v = fmaxf(v, 0.f);
            p.buf0[(size_t)(R0 + t) * HID + tid] = f2bf(v);
            s += v; s2 += v * v;
        }
        atomicAdd(&st0[tid], s);
        atomicAdd(&st0[256 + tid], s2);
    }
    syncg(p.c + 0, true);   // one-time fence pair: publishes packed weights

    // ---- layers 1-4 ----
    coeffs4(p.stats + 0 * 2048, p.g1, p.beta1, sS, sT);
    layer16(p.buf0, p.pw + 0 * 65536, p.bias1, nullptr, p.buf1,
            p.stats + 1 * 2048 + (b & 3) * 512, sS, sT, R0);
    syncg(p.c + 1, false);
    coeffs4(p.stats + 1 * 2048, p.g2, p.beta2, sS, sT);
    layer16(p.buf1, p.pw + 1 * 65536, p.bias2, p.buf0, p.buf2,
            p.stats + 2 * 2048 + (b & 3) * 512, sS, sT, R0);
    syncg(p.c + 2, false);
    coeffs4(p.stats + 2 * 2048, p.g1 + HID, p.beta1 + HID, sS, sT);
    layer16(p.buf2, p.pw + 2 * 65536, p.bias1 + HID, nullptr, p.buf1,
            p.stats + 3 * 2048 + (b & 3) * 512, sS, sT, R0);
    syncg(p.c + 3, false);
    coeffs4(p.stats + 3 * 2048, p.g2 + HID, p.beta2 + HID, sS, sT);
    layer16(p.buf1, p.pw + 3 * 65536, p.bias2 + HID, p.buf2, p.buf0,
            p.stats + 4 * 2048 + (b & 3) * 512, sS, sT, R0);
    syncg(p.c + 4, false);

    // ---- final: BN+ReLU + W_out (81 cols) + symmetric scatter ----
    coeffs4(p.stats + 4 * 2048, p.fg, p.fbeta, sS, sT);
    {
        int lane = tid & 63, wid = tid >> 6;
        int r16 = lane & 15, kq = lane >> 4;
        const ushort* xr = p.buf0 + (size_t)(R0 + r16) * HID;
        const ushort* po = p.pw + 4 * 65536;
        for (int f = wid; f < 6; f += 4) {
            f32x4 acc = {};
#pragma unroll
            for (int kk = 0; kk < 8; kk++) {
                int kst = kk * 32 + kq * 8;
                bf8 af = ldA(xr, kst, sS, sT);
                bf8 bv = *(const bf8*)(po + ((f * 8 + kk) << 9) + lane * 8);
                acc = __builtin_amdgcn_mfma_f32_16x16x32_bf16(af, bv, acc, 0, 0, 0);
            }
            int t = f * 16 + r16;
            if (t < 81) {
                int gi = t / 9, gj = t - gi * 9;
                int ttr = gj * 9 + gi;
                float bb = p.b_out[t];
#pragma unroll
                for (int i = 0; i < 4; i++) {
                    int r = R0 + kq * 4 + i;
                    int2 ij = pairs_s[kq * 4 + i];
                    int batch = r / PAIRS;
                    size_t base1 = ((size_t)(batch * NB_VAR + ij.x) * NB_VAR + ij.y) * 81;
                    size_t base2 = ((size_t)(batch * NB_VAR + ij.y) * NB_VAR + ij.x) * 81;
                    float v = acc[i] + bb;
                    p.out[base1 + t] = v;
                    p.out[base2 + ttr] = v;
                }
            }
        }
    }
}

extern "C" void kernel_launch(void* const* d_in, const int* in_sizes, int n_in,
                              void* d_out, int out_size, void* d_ws, size_t ws_size,
                              hipStream_t stream) {
    KP p;
    p.x     = (const float*)d_in[0];
    p.w_in  = (const float*)d_in[1];
    p.b_in  = (const float*)d_in[2];
    p.g1    = (const float*)d_in[3];
    p.beta1 = (const float*)d_in[4];
    p.w1    = (const float*)d_in[5];
    p.bias1 = (const float*)d_in[6];
    p.g2    = (const float*)d_in[7];
    p.beta2 = (const float*)d_in[8];
    p.w2    = (const float*)d_in[9];
    p.bias2 = (const float*)d_in[10];
    p.fg    = (const float*)d_in[11];
    p.fbeta = (const float*)d_in[12];
    p.w_out = (const float*)d_in[13];
    p.b_out = (const float*)d_in[14];
    p.out   = (float*)d_out;

    p.buf0 = (ushort*)d_ws;
    p.buf1 = p.buf0 + (size_t)RTOT * HID;
    p.buf2 = p.buf1 + (size_t)RTOT * HID;
    p.pw   = p.buf2 + (size_t)RTOT * HID;        // 262144 + 24576 ushort
    p.stats = (float*)(p.pw + 262144 + 24576);   // 5 x 2048 floats
    p.c     = (int*)(p.stats + 5 * 2048);        // 8 ints

    hipMemsetAsync(p.stats, 0, 5 * 2048 * sizeof(float) + 8 * sizeof(int), stream);
    fused<<<NBLK, NTHR, 0, stream>>>(p);
}

// Round 10
// 100.529 us; speedup vs baseline: 3.4711x; 3.4711x over previous
//
#include <hip/hip_runtime.h>

#define RTOT 12960      // 4 * 3240 rows
#define PAIRS 3240
#define NB_VAR 81
#define HID 256
#define EPS 1e-5f

#define BM 64
#define BN 64
#define NRT 203        // ceil(12960/64) row tiles
#define LDB 264        // sB row stride in bf16: 528 B/row -> 2-way bank alias max (free per m136)
#define NCPY 16        // stats accumulator split: 812 blocks / 16 copies ~ 25 RMW/addr (was 406)

using bf8   = __attribute__((ext_vector_type(8))) short;
using f32x4 = __attribute__((ext_vector_type(4))) float;

__device__ inline ushort f2bf(float f) {
    union { float f; unsigned u; } c; c.f = f;
    unsigned u = c.u + 0x7fffu + ((c.u >> 16) & 1u);
    return (ushort)(u >> 16);
}
__device__ inline float bf2f(ushort h) {
    union { unsigned u; float f; } c; c.u = (unsigned)h << 16;
    return c.f;
}
__device__ inline unsigned pk2(float a, float b) {
    return (unsigned)f2bf(a) | ((unsigned)f2bf(b) << 16);
}
// upper-tri pair from linear index p (0..3239)
__device__ inline int2 pair_of(int p) {
    int i = (int)((161.0 - sqrt(25921.0 - 8.0 * (double)p)) * 0.5);
    if (i < 0) i = 0;
    while ((161 * (i + 1) - (i + 1) * (i + 1)) / 2 <= p) i++;
    while ((161 * i - i * i) / 2 > p) i--;
    int j = i + 1 + (p - (161 * i - i * i) / 2);
    return make_int2(i, j);
}

// sum the NCPY split copies -> BN coefficients in LDS
__device__ __forceinline__ void coeffs(const float* __restrict__ st,
                                       const float* __restrict__ g,
                                       const float* __restrict__ beta,
                                       float* sS, float* sT) {
    int tid = threadIdx.x;
    float s = 0.f, q = 0.f;
#pragma unroll
    for (int cp = 0; cp < NCPY; cp++) {
        s += st[cp * 512 + tid];
        q += st[cp * 512 + 256 + tid];
    }
    float m = s * (1.f / RTOT);
    float v = q * (1.f / RTOT) - m * m;
    float sc = g[tid] * rsqrtf(v + EPS);
    sS[tid] = sc;
    sT[tid] = fmaf(-m, sc, beta[tid]);
}

// ---------------- init: weights->bf16, pairs, zero out-diag, input proj + stats0 ----------------
__global__ __launch_bounds__(256) void k_init(
        const float* __restrict__ x, const float* __restrict__ w_in,
        const float* __restrict__ b_in,
        const float* __restrict__ w1, const float* __restrict__ w2,
        const float* __restrict__ w_out, ushort* __restrict__ wbf,
        int2* __restrict__ pairs, float* __restrict__ out,
        ushort* __restrict__ h0, float* __restrict__ st) {
    __shared__ float feat[32][4];
    int tid = threadIdx.x;
    int gtid = blockIdx.x * 256 + tid;

    for (int i = gtid; i < 262144 + 81 * 256; i += 405 * 256) {
        float v;
        if (i < 131072)      v = w1[i];
        else if (i < 262144) v = w2[i - 131072];
        else                 v = w_out[i - 262144];
        wbf[i] = f2bf(v);
    }
    if (gtid < 4 * NB_VAR * 81) {
        int b = gtid / (NB_VAR * 81);
        int rem = gtid - b * (NB_VAR * 81);
        int i = rem / 81, t = rem - i * 81;
        out[((size_t)(b * NB_VAR + i) * NB_VAR + i) * 81 + t] = 0.f;
    }

    int r0 = blockIdx.x * 32;
    if (tid < 32) {
        int r = r0 + tid;
        int b = r / PAIRS, p = r - b * PAIRS;
        int2 ij = pair_of(p);
        if (r < PAIRS) pairs[r] = ij;
        const float* xb = x + b * NB_VAR * 2;
        feat[tid][0] = xb[ij.x * 2 + 0];
        feat[tid][1] = xb[ij.x * 2 + 1];
        feat[tid][2] = xb[ij.y * 2 + 0];
        feat[tid][3] = xb[ij.y * 2 + 1];
    }
    __syncthreads();
    float4 w = ((const float4*)w_in)[tid];
    float bi = b_in[tid];
    float s = 0.f, s2 = 0.f;
    for (int t = 0; t < 32; t++) {
        float v = fmaf(feat[t][0], w.x, fmaf(feat[t][1], w.y,
                  fmaf(feat[t][2], w.z, fmaf(feat[t][3], w.w, bi))));
        v = fmaxf(v, 0.f);
        h0[(size_t)(r0 + t) * HID + tid] = f2bf(v);
        s += v; s2 += v * v;
    }
    int cp = blockIdx.x & (NCPY - 1);
    atomicAdd(&st[cp * 512 + tid], s);
    atomicAdd(&st[cp * 512 + 256 + tid], s2);
}

// ---------------- MFMA GEMM, barrier-free K-loop (R6 structure + split stats) ----------------
__global__ __launch_bounds__(256) void k_gemm(
        const ushort* __restrict__ X, const float* __restrict__ stin,
        const float* __restrict__ g, const float* __restrict__ beta,
        const ushort* __restrict__ Wb, const float* __restrict__ bias,
        const ushort* __restrict__ res, ushort* __restrict__ Y,
        float* __restrict__ stout) {
    __shared__ ushort sB[BN * LDB];
    __shared__ float sS[HID], sT[HID];
    __shared__ float sCS[2][BN], sCQ[2][BN];

    int tid = threadIdx.x;
    coeffs(stin, g, beta, sS, sT);

    int bm0 = blockIdx.x * BM;
    int bn0 = blockIdx.y * BN;
    {   // stage whole B tile: 64 rows x 256 k
        int row = tid >> 2, cq = tid & 3;
#pragma unroll
        for (int s = 0; s < 8; s++) {
            int col = cq * 8 + s * 32;
            uint4 wv = *(const uint4*)(Wb + (size_t)(bn0 + row) * HID + col);
            *(uint4*)&sB[row * LDB + col] = wv;
        }
    }
    __syncthreads();

    int lane = tid & 63, wid = tid >> 6;
    int wr = wid >> 1, wc = wid & 1;
    int r16 = lane & 15, kq = lane >> 4;

    f32x4 acc[2][2] = {};
    int ar0 = min(bm0 + wr * 32 + r16, RTOT - 1);
    int ar1 = min(bm0 + wr * 32 + 16 + r16, RTOT - 1);

#pragma unroll
    for (int kk = 0; kk < 8; kk++) {
        int kst = kk * 32 + kq * 8;
        float4 s0 = *(const float4*)&sS[kst], s1 = *(const float4*)&sS[kst + 4];
        float4 t0 = *(const float4*)&sT[kst], t1 = *(const float4*)&sT[kst + 4];
        bf8 af[2];
#pragma unroll
        for (int m = 0; m < 2; m++) {
            ushort xv[8];
            *(uint4*)xv = *(const uint4*)(X + (size_t)(m ? ar1 : ar0) * HID + kst);
            unsigned pk[4];
            pk[0] = pk2(fmaxf(fmaf(bf2f(xv[0]), s0.x, t0.x), 0.f),
                        fmaxf(fmaf(bf2f(xv[1]), s0.y, t0.y), 0.f));
            pk[1] = pk2(fmaxf(fmaf(bf2f(xv[2]), s0.z, t0.z), 0.f),
                        fmaxf(fmaf(bf2f(xv[3]), s0.w, t0.w), 0.f));
            pk[2] = pk2(fmaxf(fmaf(bf2f(xv[4]), s1.x, t1.x), 0.f),
                        fmaxf(fmaf(bf2f(xv[5]), s1.y, t1.y), 0.f));
            pk[3] = pk2(fmaxf(fmaf(bf2f(xv[6]), s1.z, t1.z), 0.f),
                        fmaxf(fmaf(bf2f(xv[7]), s1.w, t1.w), 0.f));
            af[m] = *(bf8*)pk;
        }
        bf8 bfr[2];
#pragma unroll
        for (int n = 0; n < 2; n++)
            bfr[n] = *(const bf8*)&sB[(wc * 32 + n * 16 + r16) * LDB + kst];
#pragma unroll
        for (int m = 0; m < 2; m++)
#pragma unroll
            for (int n = 0; n < 2; n++)
                acc[m][n] = __builtin_amdgcn_mfma_f32_16x16x32_bf16(af[m], bfr[n], acc[m][n], 0, 0, 0);
    }

    // epilogue: bias (+res), store bf16, column stats
    int rb = bm0 + wr * 32;
    int cb = bn0 + wc * 32;
    float csum[2] = {0.f, 0.f}, csq[2] = {0.f, 0.f};
#pragma unroll
    for (int n = 0; n < 2; n++) {
        int col = cb + n * 16 + r16;
        float bv = bias[col];
#pragma unroll
        for (int m = 0; m < 2; m++) {
#pragma unroll
            for (int i = 0; i < 4; i++) {
                int r = rb + m * 16 + kq * 4 + i;
                if (r < RTOT) {
                    float v = acc[m][n][i] + bv;
                    if (res) v += bf2f(res[(size_t)r * HID + col]);
                    Y[(size_t)r * HID + col] = f2bf(v);
                    csum[n] += v; csq[n] += v * v;
                }
            }
        }
    }
#pragma unroll
    for (int n = 0; n < 2; n++) {
        float s = csum[n], q = csq[n];
        s += __shfl_xor(s, 16); q += __shfl_xor(q, 16);
        s += __shfl_xor(s, 32); q += __shfl_xor(q, 32);
        if (lane < 16) {
            int lc = wc * 32 + n * 16 + lane;
            sCS[wr][lc] = s; sCQ[wr][lc] = q;
        }
    }
    __syncthreads();
    if (tid < 2 * BN) {
        int col = tid & (BN - 1), q = tid >> 6;
        float v = q ? (sCQ[0][col] + sCQ[1][col]) : (sCS[0][col] + sCS[1][col]);
        int cp = (blockIdx.x + blockIdx.y) & (NCPY - 1);
        atomicAdd(&stout[cp * 512 + q * 256 + bn0 + col], v);
    }
}

// ---------------- final GEMM (N=81), barrier-free, fused symmetric scatter ----------------
__global__ __launch_bounds__(256) void k_gout(
        const ushort* __restrict__ X, const float* __restrict__ stin,
        const float* __restrict__ g, const float* __restrict__ beta,
        const ushort* __restrict__ Wb, const float* __restrict__ b_out,
        const int2* __restrict__ pairs, float* __restrict__ out) {
    __shared__ ushort sB[BN * LDB];
    __shared__ float sS[HID], sT[HID];

    int tid = threadIdx.x;
    coeffs(stin, g, beta, sS, sT);

    int bm0 = blockIdx.x * BM;
    int bn0 = blockIdx.y * BN;
    {
        int row = tid >> 2, cq = tid & 3;
        int gn = bn0 + row; gn = gn < 81 ? gn : 80;
#pragma unroll
        for (int s = 0; s < 8; s++) {
            int col = cq * 8 + s * 32;
            uint4 wv = *(const uint4*)(Wb + (size_t)gn * HID + col);
            *(uint4*)&sB[row * LDB + col] = wv;
        }
    }
    __syncthreads();

    int lane = tid & 63, wid = tid >> 6;
    int wr = wid >> 1, wc = wid & 1;
    int r16 = lane & 15, kq = lane >> 4;

    f32x4 acc[2][2] = {};
    int ar0 = min(bm0 + wr * 32 + r16, RTOT - 1);
    int ar1 = min(bm0 + wr * 32 + 16 + r16, RTOT - 1);

#pragma unroll
    for (int kk = 0; kk < 8; kk++) {
        int kst = kk * 32 + kq * 8;
        float4 s0 = *(const float4*)&sS[kst], s1 = *(const float4*)&sS[kst + 4];
        float4 t0 = *(const float4*)&sT[kst], t1 = *(const float4*)&sT[kst + 4];
        bf8 af[2];
#pragma unroll
        for (int m = 0; m < 2; m++) {
            ushort xv[8];
            *(uint4*)xv = *(const uint4*)(X + (size_t)(m ? ar1 : ar0) * HID + kst);
            unsigned pk[4];
            pk[0] = pk2(fmaxf(fmaf(bf2f(xv[0]), s0.x, t0.x), 0.f),
                        fmaxf(fmaf(bf2f(xv[1]), s0.y, t0.y), 0.f));
            pk[1] = pk2(fmaxf(fmaf(bf2f(xv[2]), s0.z, t0.z), 0.f),
                        fmaxf(fmaf(bf2f(xv[3]), s0.w, t0.w), 0.f));
            pk[2] = pk2(fmaxf(fmaf(bf2f(xv[4]), s1.x, t1.x), 0.f),
                        fmaxf(fmaf(bf2f(xv[5]), s1.y, t1.y), 0.f));
            pk[3] = pk2(fmaxf(fmaf(bf2f(xv[6]), s1.z, t1.z), 0.f),
                        fmaxf(fmaf(bf2f(xv[7]), s1.w, t1.w), 0.f));
            af[m] = *(bf8*)pk;
        }
        bf8 bfr[2];
#pragma unroll
        for (int n = 0; n < 2; n++)
            bfr[n] = *(const bf8*)&sB[(wc * 32 + n * 16 + r16) * LDB + kst];
#pragma unroll
        for (int m = 0; m < 2; m++)
#pragma unroll
            for (int n = 0; n < 2; n++)
                acc[m][n] = __builtin_amdgcn_mfma_f32_16x16x32_bf16(af[m], bfr[n], acc[m][n], 0, 0, 0);
    }

    int rb = bm0 + wr * 32;
    int cb = bn0 + wc * 32;
    int tcol[2], ttr[2]; float bv[2]; bool tok[2];
#pragma unroll
    for (int n = 0; n < 2; n++) {
        int t = cb + n * 16 + r16;
        tok[n] = t < 81;
        int tc = tok[n] ? t : 0;
        tcol[n] = tc;
        int gi = tc / 9, gj = tc - gi * 9;
        ttr[n] = gj * 9 + gi;
        bv[n] = b_out[tc];
    }
#pragma unroll
    for (int m = 0; m < 2; m++) {
#pragma unroll
        for (int i = 0; i < 4; i++) {
            int r = rb + m * 16 + kq * 4 + i;
            if (r >= RTOT) continue;
            int b = r / PAIRS, p = r - b * PAIRS;
            int2 ij = pairs[p];
            size_t base1 = ((size_t)(b * NB_VAR + ij.x) * NB_VAR + ij.y) * 81;
            size_t base2 = ((size_t)(b * NB_VAR + ij.y) * NB_VAR + ij.x) * 81;
#pragma unroll
            for (int n = 0; n < 2; n++) {
                if (!tok[n]) continue;
                float v = acc[m][n][i] + bv[n];
                out[base1 + tcol[n]] = v;
                out[base2 + ttr[n]] = v;
            }
        }
    }
}

extern "C" void kernel_launch(void* const* d_in, const int* in_sizes, int n_in,
                              void* d_out, int out_size, void* d_ws, size_t ws_size,
                              hipStream_t stream) {
    const float* x     = (const float*)d_in[0];
    const float* w_in  = (const float*)d_in[1];
    const float* b_in  = (const float*)d_in[2];
    const float* g1    = (const float*)d_in[3];
    const float* beta1 = (const float*)d_in[4];
    const float* w1    = (const float*)d_in[5];
    const float* bias1 = (const float*)d_in[6];
    const float* g2    = (const float*)d_in[7];
    const float* beta2 = (const float*)d_in[8];
    const float* w2    = (const float*)d_in[9];
    const float* bias2 = (const float*)d_in[10];
    const float* fg    = (const float*)d_in[11];
    const float* fbeta = (const float*)d_in[12];
    const float* w_out = (const float*)d_in[13];
    const float* b_out = (const float*)d_in[14];
    float* out = (float*)d_out;

    ushort* buf0 = (ushort*)d_ws;
    ushort* buf1 = buf0 + (size_t)RTOT * HID;
    ushort* buf2 = buf1 + (size_t)RTOT * HID;
    ushort* wbf  = buf2 + (size_t)RTOT * HID;   // 5*65536 elems
    float* stats = (float*)(wbf + 5 * 65536);   // 5 slots x NCPY x 512
    int2*  pairs = (int2*)(stats + 5 * NCPY * 512);
    // wbf layout: w1_0 @0, w1_1 @65536, w2_0 @131072, w2_1 @196608, w_out @262144

    hipMemsetAsync(stats, 0, 5 * NCPY * 512 * sizeof(float), stream);
    k_init<<<405, 256, 0, stream>>>(x, w_in, b_in, w1, w2, w_out, wbf,
                                    pairs, out, buf0, stats + 0 * NCPY * 512);

    dim3 gmid(NRT, HID / BN);   // (203, 4)
    dim3 gfin(NRT, 2);          // (203, 2)

    k_gemm<<<gmid, 256, 0, stream>>>(buf0, stats + 0 * NCPY * 512, g1, beta1,
                                     wbf + 0 * 65536, bias1, nullptr, buf1, stats + 1 * NCPY * 512);
    k_gemm<<<gmid, 256, 0, stream>>>(buf1, stats + 1 * NCPY * 512, g2, beta2,
                                     wbf + 2 * 65536, bias2, buf0, buf2, stats + 2 * NCPY * 512);
    k_gemm<<<gmid, 256, 0, stream>>>(buf2, stats + 2 * NCPY * 512, g1 + HID, beta1 + HID,
                                     wbf + 1 * 65536, bias1 + HID, nullptr, buf1, stats + 3 * NCPY * 512);
    k_gemm<<<gmid, 256, 0, stream>>>(buf1, stats + 3 * NCPY * 512, g2 + HID, beta2 + HID,
                                     wbf + 3 * 65536, bias2 + HID, buf2, buf0, stats + 4 * NCPY * 512);
    k_gout<<<gfin, 256, 0, stream>>>(buf0, stats + 4 * NCPY * 512, fg, fbeta,
                                     wbf + 4 * 65536, b_out, pairs, out);
}

// Round 11
// 92.994 us; speedup vs baseline: 3.7524x; 1.0810x over previous
//
#include <hip/hip_runtime.h>

#define RTOT 12960      // 4 * 3240 rows
#define PAIRS 3240
#define NB_VAR 81
#define HID 256
#define EPS 1e-5f

#define BM 64
#define BN 64
#define NRT 203        // ceil(12960/64) row tiles
#define LDB 264        // sB row stride in bf16: 528 B/row -> 2-way bank alias max (free per m136)
#define NCPY 16        // stats accumulator split: ~51 blocks/copy -> low RMW contention

using bf8   = __attribute__((ext_vector_type(8))) short;
using f32x4 = __attribute__((ext_vector_type(4))) float;

__device__ inline ushort f2bf(float f) {
    union { float f; unsigned u; } c; c.f = f;
    unsigned u = c.u + 0x7fffu + ((c.u >> 16) & 1u);
    return (ushort)(u >> 16);
}
__device__ inline float bf2f(ushort h) {
    union { unsigned u; float f; } c; c.u = (unsigned)h << 16;
    return c.f;
}
__device__ inline unsigned pk2(float a, float b) {
    return (unsigned)f2bf(a) | ((unsigned)f2bf(b) << 16);
}
// upper-tri pair from linear index p (0..3239)
__device__ inline int2 pair_of(int p) {
    int i = (int)((161.0 - sqrt(25921.0 - 8.0 * (double)p)) * 0.5);
    if (i < 0) i = 0;
    while ((161 * (i + 1) - (i + 1) * (i + 1)) / 2 <= p) i++;
    while ((161 * i - i * i) / 2 > p) i--;
    int j = i + 1 + (p - (161 * i - i * i) / 2);
    return make_int2(i, j);
}

// sum the NCPY split copies -> BN coefficients in LDS
__device__ __forceinline__ void coeffs(const float* __restrict__ st,
                                       const float* __restrict__ g,
                                       const float* __restrict__ beta,
                                       float* sS, float* sT) {
    int tid = threadIdx.x;
    float s = 0.f, q = 0.f;
#pragma unroll
    for (int cp = 0; cp < NCPY; cp++) {
        s += st[cp * 512 + tid];
        q += st[cp * 512 + 256 + tid];
    }
    float m = s * (1.f / RTOT);
    float v = q * (1.f / RTOT) - m * m;
    float sc = g[tid] * rsqrtf(v + EPS);
    sS[tid] = sc;
    sT[tid] = fmaf(-m, sc, beta[tid]);
}

// ---------------- init: weights->bf16, pairs, zero out-diag, input proj + stats0 ----------------
__global__ __launch_bounds__(256) void k_init(
        const float* __restrict__ x, const float* __restrict__ w_in,
        const float* __restrict__ b_in,
        const float* __restrict__ w1, const float* __restrict__ w2,
        const float* __restrict__ w_out, ushort* __restrict__ wbf,
        int2* __restrict__ pairs, float* __restrict__ out,
        ushort* __restrict__ h0, float* __restrict__ st) {
    __shared__ float feat[32][4];
    int tid = threadIdx.x;
    int gtid = blockIdx.x * 256 + tid;

    for (int i = gtid; i < 262144 + 81 * 256; i += 405 * 256) {
        float v;
        if (i < 131072)      v = w1[i];
        else if (i < 262144) v = w2[i - 131072];
        else                 v = w_out[i - 262144];
        wbf[i] = f2bf(v);
    }
    if (gtid < 4 * NB_VAR * 81) {
        int b = gtid / (NB_VAR * 81);
        int rem = gtid - b * (NB_VAR * 81);
        int i = rem / 81, t = rem - i * 81;
        out[((size_t)(b * NB_VAR + i) * NB_VAR + i) * 81 + t] = 0.f;
    }

    int r0 = blockIdx.x * 32;
    if (tid < 32) {
        int r = r0 + tid;
        int b = r / PAIRS, p = r - b * PAIRS;
        int2 ij = pair_of(p);
        if (r < PAIRS) pairs[r] = ij;
        const float* xb = x + b * NB_VAR * 2;
        feat[tid][0] = xb[ij.x * 2 + 0];
        feat[tid][1] = xb[ij.x * 2 + 1];
        feat[tid][2] = xb[ij.y * 2 + 0];
        feat[tid][3] = xb[ij.y * 2 + 1];
    }
    __syncthreads();
    float4 w = ((const float4*)w_in)[tid];
    float bi = b_in[tid];
    float s = 0.f, s2 = 0.f;
    for (int t = 0; t < 32; t++) {
        float v = fmaf(feat[t][0], w.x, fmaf(feat[t][1], w.y,
                  fmaf(feat[t][2], w.z, fmaf(feat[t][3], w.w, bi))));
        v = fmaxf(v, 0.f);
        h0[(size_t)(r0 + t) * HID + tid] = f2bf(v);
        s += v; s2 += v * v;
    }
    int cp = blockIdx.x & (NCPY - 1);
    atomicAdd(&st[cp * 512 + tid], s);
    atomicAdd(&st[cp * 512 + 256 + tid], s2);
}

// ---------------- MFMA GEMM, barrier-free K-loop, XCD-swizzled 1D grid (812) ----------------
// Swizzle: the 4 col-blocks sharing a row-tile get ids congruent mod 8 -> same XCD ->
// A-rows are fetched into that XCD's L2 once and reused 4x (T1 mechanism, bijective incl. tail).
__global__ __launch_bounds__(256) void k_gemm(
        const ushort* __restrict__ X, const float* __restrict__ stin,
        const float* __restrict__ g, const float* __restrict__ beta,
        const ushort* __restrict__ Wb, const float* __restrict__ bias,
        const ushort* __restrict__ res, ushort* __restrict__ Y,
        float* __restrict__ stout) {
    __shared__ ushort sB[BN * LDB];
    __shared__ float sS[HID], sT[HID];
    __shared__ float sCS[2][BN], sCQ[2][BN];

    int tid = threadIdx.x;
    coeffs(stin, g, beta, sS, sT);

    int id = blockIdx.x, bx, by;
    if (id < 800) { bx = (id >> 5) * 8 + (id & 7); by = (id >> 3) & 3; }
    else          { int j = id - 800; bx = 200 + (j >> 2); by = j & 3; }

    int bm0 = bx * BM;
    int bn0 = by * BN;
    {   // stage whole B tile: 64 rows x 256 k
        int row = tid >> 2, cq = tid & 3;
#pragma unroll
        for (int s = 0; s < 8; s++) {
            int col = cq * 8 + s * 32;
            uint4 wv = *(const uint4*)(Wb + (size_t)(bn0 + row) * HID + col);
            *(uint4*)&sB[row * LDB + col] = wv;
        }
    }
    __syncthreads();

    int lane = tid & 63, wid = tid >> 6;
    int wr = wid >> 1, wc = wid & 1;
    int r16 = lane & 15, kq = lane >> 4;

    f32x4 acc[2][2] = {};
    int ar0 = min(bm0 + wr * 32 + r16, RTOT - 1);
    int ar1 = min(bm0 + wr * 32 + 16 + r16, RTOT - 1);

#pragma unroll
    for (int kk = 0; kk < 8; kk++) {
        int kst = kk * 32 + kq * 8;
        float4 s0 = *(const float4*)&sS[kst], s1 = *(const float4*)&sS[kst + 4];
        float4 t0 = *(const float4*)&sT[kst], t1 = *(const float4*)&sT[kst + 4];
        bf8 af[2];
#pragma unroll
        for (int m = 0; m < 2; m++) {
            ushort xv[8];
            *(uint4*)xv = *(const uint4*)(X + (size_t)(m ? ar1 : ar0) * HID + kst);
            unsigned pk[4];
            pk[0] = pk2(fmaxf(fmaf(bf2f(xv[0]), s0.x, t0.x), 0.f),
                        fmaxf(fmaf(bf2f(xv[1]), s0.y, t0.y), 0.f));
            pk[1] = pk2(fmaxf(fmaf(bf2f(xv[2]), s0.z, t0.z), 0.f),
                        fmaxf(fmaf(bf2f(xv[3]), s0.w, t0.w), 0.f));
            pk[2] = pk2(fmaxf(fmaf(bf2f(xv[4]), s1.x, t1.x), 0.f),
                        fmaxf(fmaf(bf2f(xv[5]), s1.y, t1.y), 0.f));
            pk[3] = pk2(fmaxf(fmaf(bf2f(xv[6]), s1.z, t1.z), 0.f),
                        fmaxf(fmaf(bf2f(xv[7]), s1.w, t1.w), 0.f));
            af[m] = *(bf8*)pk;
        }
        bf8 bfr[2];
#pragma unroll
        for (int n = 0; n < 2; n++)
            bfr[n] = *(const bf8*)&sB[(wc * 32 + n * 16 + r16) * LDB + kst];
#pragma unroll
        for (int m = 0; m < 2; m++)
#pragma unroll
            for (int n = 0; n < 2; n++)
                acc[m][n] = __builtin_amdgcn_mfma_f32_16x16x32_bf16(af[m], bfr[n], acc[m][n], 0, 0, 0);
    }

    // epilogue: bias (+res), store bf16, column stats
    int rb = bm0 + wr * 32;
    int cb = bn0 + wc * 32;
    float csum[2] = {0.f, 0.f}, csq[2] = {0.f, 0.f};
#pragma unroll
    for (int n = 0; n < 2; n++) {
        int col = cb + n * 16 + r16;
        float bv = bias[col];
#pragma unroll
        for (int m = 0; m < 2; m++) {
#pragma unroll
            for (int i = 0; i < 4; i++) {
                int r = rb + m * 16 + kq * 4 + i;
                if (r < RTOT) {
                    float v = acc[m][n][i] + bv;
                    if (res) v += bf2f(res[(size_t)r * HID + col]);
                    Y[(size_t)r * HID + col] = f2bf(v);
                    csum[n] += v; csq[n] += v * v;
                }
            }
        }
    }
#pragma unroll
    for (int n = 0; n < 2; n++) {
        float s = csum[n], q = csq[n];
        s += __shfl_xor(s, 16); q += __shfl_xor(q, 16);
        s += __shfl_xor(s, 32); q += __shfl_xor(q, 32);
        if (lane < 16) {
            int lc = wc * 32 + n * 16 + lane;
            sCS[wr][lc] = s; sCQ[wr][lc] = q;
        }
    }
    __syncthreads();
    if (tid < 2 * BN) {
        int col = tid & (BN - 1), q = tid >> 6;
        float v = q ? (sCQ[0][col] + sCQ[1][col]) : (sCS[0][col] + sCS[1][col]);
        int cp = id & (NCPY - 1);
        atomicAdd(&stout[cp * 512 + q * 256 + bn0 + col], v);
    }
}

// ---------------- final GEMM (N=81), barrier-free, fused scatter, XCD-swizzled (406) ----------------
__global__ __launch_bounds__(256) void k_gout(
        const ushort* __restrict__ X, const float* __restrict__ stin,
        const float* __restrict__ g, const float* __restrict__ beta,
        const ushort* __restrict__ Wb, const float* __restrict__ b_out,
        const int2* __restrict__ pairs, float* __restrict__ out) {
    __shared__ ushort sB[BN * LDB];
    __shared__ float sS[HID], sT[HID];

    int tid = threadIdx.x;
    coeffs(stin, g, beta, sS, sT);

    int id = blockIdx.x, bx, by;
    if (id < 400) { bx = (id >> 4) * 8 + (id & 7); by = (id >> 3) & 1; }
    else          { int j = id - 400; bx = 200 + (j >> 1); by = j & 1; }

    int bm0 = bx * BM;
    int bn0 = by * BN;
    {
        int row = tid >> 2, cq = tid & 3;
        int gn = bn0 + row; gn = gn < 81 ? gn : 80;
#pragma unroll
        for (int s = 0; s < 8; s++) {
            int col = cq * 8 + s * 32;
            uint4 wv = *(const uint4*)(Wb + (size_t)gn * HID + col);
            *(uint4*)&sB[row * LDB + col] = wv;
        }
    }
    __syncthreads();

    int lane = tid & 63, wid = tid >> 6;
    int wr = wid >> 1, wc = wid & 1;
    int r16 = lane & 15, kq = lane >> 4;

    f32x4 acc[2][2] = {};
    int ar0 = min(bm0 + wr * 32 + r16, RTOT - 1);
    int ar1 = min(bm0 + wr * 32 + 16 + r16, RTOT - 1);

#pragma unroll
    for (int kk = 0; kk < 8; kk++) {
        int kst = kk * 32 + kq * 8;
        float4 s0 = *(const float4*)&sS[kst], s1 = *(const float4*)&sS[kst + 4];
        float4 t0 = *(const float4*)&sT[kst], t1 = *(const float4*)&sT[kst + 4];
        bf8 af[2];
#pragma unroll
        for (int m = 0; m < 2; m++) {
            ushort xv[8];
            *(uint4*)xv = *(const uint4*)(X + (size_t)(m ? ar1 : ar0) * HID + kst);
            unsigned pk[4];
            pk[0] = pk2(fmaxf(fmaf(bf2f(xv[0]), s0.x, t0.x), 0.f),
                        fmaxf(fmaf(bf2f(xv[1]), s0.y, t0.y), 0.f));
            pk[1] = pk2(fmaxf(fmaf(bf2f(xv[2]), s0.z, t0.z), 0.f),
                        fmaxf(fmaf(bf2f(xv[3]), s0.w, t0.w), 0.f));
            pk[2] = pk2(fmaxf(fmaf(bf2f(xv[4]), s1.x, t1.x), 0.f),
                        fmaxf(fmaf(bf2f(xv[5]), s1.y, t1.y), 0.f));
            pk[3] = pk2(fmaxf(fmaf(bf2f(xv[6]), s1.z, t1.z), 0.f),
                        fmaxf(fmaf(bf2f(xv[7]), s1.w, t1.w), 0.f));
            af[m] = *(bf8*)pk;
        }
        bf8 bfr[2];
#pragma unroll
        for (int n = 0; n < 2; n++)
            bfr[n] = *(const bf8*)&sB[(wc * 32 + n * 16 + r16) * LDB + kst];
#pragma unroll
        for (int m = 0; m < 2; m++)
#pragma unroll
            for (int n = 0; n < 2; n++)
                acc[m][n] = __builtin_amdgcn_mfma_f32_16x16x32_bf16(af[m], bfr[n], acc[m][n], 0, 0, 0);
    }

    int rb = bm0 + wr * 32;
    int cb = bn0 + wc * 32;
    int tcol[2], ttr[2]; float bv[2]; bool tok[2];
#pragma unroll
    for (int n = 0; n < 2; n++) {
        int t = cb + n * 16 + r16;
        tok[n] = t < 81;
        int tc = tok[n] ? t : 0;
        tcol[n] = tc;
        int gi = tc / 9, gj = tc - gi * 9;
        ttr[n] = gj * 9 + gi;
        bv[n] = b_out[tc];
    }
#pragma unroll
    for (int m = 0; m < 2; m++) {
#pragma unroll
        for (int i = 0; i < 4; i++) {
            int r = rb + m * 16 + kq * 4 + i;
            if (r >= RTOT) continue;
            int b = r / PAIRS, p = r - b * PAIRS;
            int2 ij = pairs[p];
            size_t base1 = ((size_t)(b * NB_VAR + ij.x) * NB_VAR + ij.y) * 81;
            size_t base2 = ((size_t)(b * NB_VAR + ij.y) * NB_VAR + ij.x) * 81;
#pragma unroll
            for (int n = 0; n < 2; n++) {
                if (!tok[n]) continue;
                float v = acc[m][n][i] + bv[n];
                out[base1 + tcol[n]] = v;
                out[base2 + ttr[n]] = v;
            }
        }
    }
}

extern "C" void kernel_launch(void* const* d_in, const int* in_sizes, int n_in,
                              void* d_out, int out_size, void* d_ws, size_t ws_size,
                              hipStream_t stream) {
    const float* x     = (const float*)d_in[0];
    const float* w_in  = (const float*)d_in[1];
    const float* b_in  = (const float*)d_in[2];
    const float* g1    = (const float*)d_in[3];
    const float* beta1 = (const float*)d_in[4];
    const float* w1    = (const float*)d_in[5];
    const float* bias1 = (const float*)d_in[6];
    const float* g2    = (const float*)d_in[7];
    const float* beta2 = (const float*)d_in[8];
    const float* w2    = (const float*)d_in[9];
    const float* bias2 = (const float*)d_in[10];
    const float* fg    = (const float*)d_in[11];
    const float* fbeta = (const float*)d_in[12];
    const float* w_out = (const float*)d_in[13];
    const float* b_out = (const float*)d_in[14];
    float* out = (float*)d_out;

    ushort* buf0 = (ushort*)d_ws;
    ushort* buf1 = buf0 + (size_t)RTOT * HID;
    ushort* buf2 = buf1 + (size_t)RTOT * HID;
    ushort* wbf  = buf2 + (size_t)RTOT * HID;   // 5*65536 elems
    float* stats = (float*)(wbf + 5 * 65536);   // 5 slots x NCPY x 512
    int2*  pairs = (int2*)(stats + 5 * NCPY * 512);
    // wbf layout: w1_0 @0, w1_1 @65536, w2_0 @131072, w2_1 @196608, w_out @262144

    hipMemsetAsync(stats, 0, 5 * NCPY * 512 * sizeof(float), stream);
    k_init<<<405, 256, 0, stream>>>(x, w_in, b_in, w1, w2, w_out, wbf,
                                    pairs, out, buf0, stats + 0 * NCPY * 512);

    k_gemm<<<812, 256, 0, stream>>>(buf0, stats + 0 * NCPY * 512, g1, beta1,
                                    wbf + 0 * 65536, bias1, nullptr, buf1, stats + 1 * NCPY * 512);
    k_gemm<<<812, 256, 0, stream>>>(buf1, stats + 1 * NCPY * 512, g2, beta2,
                                    wbf + 2 * 65536, bias2, buf0, buf2, stats + 2 * NCPY * 512);
    k_gemm<<<812, 256, 0, stream>>>(buf2, stats + 2 * NCPY * 512, g1 + HID, beta1 + HID,
                                    wbf + 1 * 65536, bias1 + HID, nullptr, buf1, stats + 3 * NCPY * 512);
    k_gemm<<<812, 256, 0, stream>>>(buf1, stats + 3 * NCPY * 512, g2 + HID, beta2 + HID,
                                    wbf + 3 * 65536, bias2 + HID, buf2, buf0, stats + 4 * NCPY * 512);
    k_gout<<<406, 256, 0, stream>>>(buf0, stats + 4 * NCPY * 512, fg, fbeta,
                                    wbf + 4 * 65536, b_out, pairs, out);
}

// Round 12
// 81.311 us; speedup vs baseline: 4.2915x; 1.1437x over previous
//
#include <hip/hip_runtime.h>

#define RTOT 12960      // 4 * 3240 rows
#define PAIRS 3240
#define NB_VAR 81
#define HID 256
#define EPS 1e-5f

#define BM 64
#define BN 64
#define LDB 264        // sB row stride in bf16: 528 B/row -> 2-way bank alias max (free per m136)
#define NCPY 16        // stats accumulator split: ~51 blocks/copy -> low RMW contention

using bf8   = __attribute__((ext_vector_type(8))) short;
using f32x4 = __attribute__((ext_vector_type(4))) float;

__device__ inline ushort f2bf(float f) {
    union { float f; unsigned u; } c; c.f = f;
    unsigned u = c.u + 0x7fffu + ((c.u >> 16) & 1u);
    return (ushort)(u >> 16);
}
__device__ inline float bf2f(ushort h) {
    union { unsigned u; float f; } c; c.u = (unsigned)h << 16;
    return c.f;
}
__device__ inline unsigned pk2(float a, float b) {
    return (unsigned)f2bf(a) | ((unsigned)f2bf(b) << 16);
}
// upper-tri pair from linear index p (0..3239)
__device__ inline int2 pair_of(int p) {
    int i = (int)((161.0 - sqrt(25921.0 - 8.0 * (double)p)) * 0.5);
    if (i < 0) i = 0;
    while ((161 * (i + 1) - (i + 1) * (i + 1)) / 2 <= p) i++;
    while ((161 * i - i * i) / 2 > p) i--;
    int j = i + 1 + (p - (161 * i - i * i) / 2);
    return make_int2(i, j);
}

// sum the NCPY split copies -> BN coefficients in LDS
__device__ __forceinline__ void coeffs(const float* __restrict__ st,
                                       const float* __restrict__ g,
                                       const float* __restrict__ beta,
                                       float* sS, float* sT) {
    int tid = threadIdx.x;
    float s = 0.f, q = 0.f;
#pragma unroll
    for (int cp = 0; cp < NCPY; cp++) {
        s += st[cp * 512 + tid];
        q += st[cp * 512 + 256 + tid];
    }
    float m = s * (1.f / RTOT);
    float v = q * (1.f / RTOT) - m * m;
    float sc = g[tid] * rsqrtf(v + EPS);
    sS[tid] = sc;
    sT[tid] = fmaf(-m, sc, beta[tid]);
}

// A-fragment: 8 bf16, BN+ReLU in registers, repack bf16 (done ONCE per element now)
__device__ __forceinline__ bf8 ldA(const ushort* xr, int kst,
                                   const float* sS, const float* sT) {
    float4 s0 = *(const float4*)&sS[kst], s1 = *(const float4*)&sS[kst + 4];
    float4 t0 = *(const float4*)&sT[kst], t1 = *(const float4*)&sT[kst + 4];
    ushort xv[8];
    *(uint4*)xv = *(const uint4*)(xr + kst);
    unsigned pk[4];
    pk[0] = pk2(fmaxf(fmaf(bf2f(xv[0]), s0.x, t0.x), 0.f),
                fmaxf(fmaf(bf2f(xv[1]), s0.y, t0.y), 0.f));
    pk[1] = pk2(fmaxf(fmaf(bf2f(xv[2]), s0.z, t0.z), 0.f),
                fmaxf(fmaf(bf2f(xv[3]), s0.w, t0.w), 0.f));
    pk[2] = pk2(fmaxf(fmaf(bf2f(xv[4]), s1.x, t1.x), 0.f),
                fmaxf(fmaf(bf2f(xv[5]), s1.y, t1.y), 0.f));
    pk[3] = pk2(fmaxf(fmaf(bf2f(xv[6]), s1.z, t1.z), 0.f),
                fmaxf(fmaf(bf2f(xv[7]), s1.w, t1.w), 0.f));
    return *(bf8*)pk;
}

// ---------------- init: weights->bf16, pairs, zero out-diag, input proj + stats0 ----------------
__global__ __launch_bounds__(256) void k_init(
        const float* __restrict__ x, const float* __restrict__ w_in,
        const float* __restrict__ b_in,
        const float* __restrict__ w1, const float* __restrict__ w2,
        const float* __restrict__ w_out, ushort* __restrict__ wbf,
        int2* __restrict__ pairs, float* __restrict__ out,
        ushort* __restrict__ h0, float* __restrict__ st) {
    __shared__ float feat[32][4];
    int tid = threadIdx.x;
    int gtid = blockIdx.x * 256 + tid;

    for (int i = gtid; i < 262144 + 81 * 256; i += 405 * 256) {
        float v;
        if (i < 131072)      v = w1[i];
        else if (i < 262144) v = w2[i - 131072];
        else                 v = w_out[i - 262144];
        wbf[i] = f2bf(v);
    }
    if (gtid < 4 * NB_VAR * 81) {
        int b = gtid / (NB_VAR * 81);
        int rem = gtid - b * (NB_VAR * 81);
        int i = rem / 81, t = rem - i * 81;
        out[((size_t)(b * NB_VAR + i) * NB_VAR + i) * 81 + t] = 0.f;
    }

    int r0 = blockIdx.x * 32;
    if (tid < 32) {
        int r = r0 + tid;
        int b = r / PAIRS, p = r - b * PAIRS;
        int2 ij = pair_of(p);
        if (r < PAIRS) pairs[r] = ij;
        const float* xb = x + b * NB_VAR * 2;
        feat[tid][0] = xb[ij.x * 2 + 0];
        feat[tid][1] = xb[ij.x * 2 + 1];
        feat[tid][2] = xb[ij.y * 2 + 0];
        feat[tid][3] = xb[ij.y * 2 + 1];
    }
    __syncthreads();
    float4 w = ((const float4*)w_in)[tid];
    float bi = b_in[tid];
    float s = 0.f, s2 = 0.f;
    for (int t = 0; t < 32; t++) {
        float v = fmaf(feat[t][0], w.x, fmaf(feat[t][1], w.y,
                  fmaf(feat[t][2], w.z, fmaf(feat[t][3], w.w, bi))));
        v = fmaxf(v, 0.f);
        h0[(size_t)(r0 + t) * HID + tid] = f2bf(v);
        s += v; s2 += v * v;
    }
    int cp = blockIdx.x & (NCPY - 1);
    atomicAdd(&st[cp * 512 + tid], s);
    atomicAdd(&st[cp * 512 + 256 + tid], s2);
}

// ---------------- MFMA GEMM: disjoint 16-row wave strips (BN work once/element) ----------------
// XCD swizzle: 4 col-blocks of a row-tile -> same XCD (T1); bijective incl. tail.
__global__ __launch_bounds__(256) void k_gemm(
        const ushort* __restrict__ X, const float* __restrict__ stin,
        const float* __restrict__ g, const float* __restrict__ beta,
        const ushort* __restrict__ Wb, const float* __restrict__ bias,
        const ushort* __restrict__ res, ushort* __restrict__ Y,
        float* __restrict__ stout) {
    __shared__ ushort sB[BN * LDB];
    __shared__ float sS[HID], sT[HID];
    __shared__ float sCS[4][BN], sCQ[4][BN];

    int tid = threadIdx.x;
    coeffs(stin, g, beta, sS, sT);

    int id = blockIdx.x, bx, by;
    if (id < 800) { bx = (id >> 5) * 8 + (id & 7); by = (id >> 3) & 3; }
    else          { int j = id - 800; bx = 200 + (j >> 2); by = j & 3; }

    int bm0 = bx * BM;
    int bn0 = by * BN;
    {   // stage whole B tile: 64 rows x 256 k
        int row = tid >> 2, cq = tid & 3;
#pragma unroll
        for (int s = 0; s < 8; s++) {
            int col = cq * 8 + s * 32;
            uint4 wv = *(const uint4*)(Wb + (size_t)(bn0 + row) * HID + col);
            *(uint4*)&sB[row * LDB + col] = wv;
        }
    }
    __syncthreads();

    int lane = tid & 63, w = tid >> 6;
    int r16 = lane & 15, kq = lane >> 4;

    f32x4 acc[4] = {};
    int ar = min(bm0 + w * 16 + r16, RTOT - 1);
    const ushort* xr = X + (size_t)ar * HID;

#pragma unroll
    for (int kk = 0; kk < 8; kk++) {
        int kst = kk * 32 + kq * 8;
        bf8 af = ldA(xr, kst, sS, sT);
        bf8 b0 = *(const bf8*)&sB[(0 * 16 + r16) * LDB + kst];
        bf8 b1 = *(const bf8*)&sB[(1 * 16 + r16) * LDB + kst];
        bf8 b2 = *(const bf8*)&sB[(2 * 16 + r16) * LDB + kst];
        bf8 b3 = *(const bf8*)&sB[(3 * 16 + r16) * LDB + kst];
        acc[0] = __builtin_amdgcn_mfma_f32_16x16x32_bf16(af, b0, acc[0], 0, 0, 0);
        acc[1] = __builtin_amdgcn_mfma_f32_16x16x32_bf16(af, b1, acc[1], 0, 0, 0);
        acc[2] = __builtin_amdgcn_mfma_f32_16x16x32_bf16(af, b2, acc[2], 0, 0, 0);
        acc[3] = __builtin_amdgcn_mfma_f32_16x16x32_bf16(af, b3, acc[3], 0, 0, 0);
    }

    // epilogue: bias (+res), store bf16, column stats
    int rb = bm0 + w * 16;
#pragma unroll
    for (int n = 0; n < 4; n++) {
        int col = bn0 + n * 16 + r16;
        float bv = bias[col];
        float cs = 0.f, cq2 = 0.f;
#pragma unroll
        for (int i = 0; i < 4; i++) {
            int r = rb + kq * 4 + i;
            if (r < RTOT) {
                float v = acc[n][i] + bv;
                if (res) v += bf2f(res[(size_t)r * HID + col]);
                Y[(size_t)r * HID + col] = f2bf(v);
                cs += v; cq2 += v * v;
            }
        }
        cs += __shfl_xor(cs, 16); cq2 += __shfl_xor(cq2, 16);
        cs += __shfl_xor(cs, 32); cq2 += __shfl_xor(cq2, 32);
        if (lane < 16) {
            sCS[w][n * 16 + lane] = cs; sCQ[w][n * 16 + lane] = cq2;
        }
    }
    __syncthreads();
    if (tid < 2 * BN) {
        int col = tid & (BN - 1), q = tid >> 6;
        float v = q ? (sCQ[0][col] + sCQ[1][col] + sCQ[2][col] + sCQ[3][col])
                    : (sCS[0][col] + sCS[1][col] + sCS[2][col] + sCS[3][col]);
        int cp = id & (NCPY - 1);
        atomicAdd(&stout[cp * 512 + q * 256 + bn0 + col], v);
    }
}

// ---------------- final GEMM (N=81), disjoint wave strips, fused scatter ----------------
__global__ __launch_bounds__(256) void k_gout(
        const ushort* __restrict__ X, const float* __restrict__ stin,
        const float* __restrict__ g, const float* __restrict__ beta,
        const ushort* __restrict__ Wb, const float* __restrict__ b_out,
        const int2* __restrict__ pairs, float* __restrict__ out) {
    __shared__ ushort sB[BN * LDB];
    __shared__ float sS[HID], sT[HID];

    int tid = threadIdx.x;
    coeffs(stin, g, beta, sS, sT);

    int id = blockIdx.x, bx, by;
    if (id < 400) { bx = (id >> 4) * 8 + (id & 7); by = (id >> 3) & 1; }
    else          { int j = id - 400; bx = 200 + (j >> 1); by = j & 1; }

    int bm0 = bx * BM;
    int bn0 = by * BN;
    {
        int row = tid >> 2, cq = tid & 3;
        int gn = bn0 + row; gn = gn < 81 ? gn : 80;
#pragma unroll
        for (int s = 0; s < 8; s++) {
            int col = cq * 8 + s * 32;
            uint4 wv = *(const uint4*)(Wb + (size_t)gn * HID + col);
            *(uint4*)&sB[row * LDB + col] = wv;
        }
    }
    __syncthreads();

    int lane = tid & 63, w = tid >> 6;
    int r16 = lane & 15, kq = lane >> 4;

    f32x4 acc[4] = {};
    int ar = min(bm0 + w * 16 + r16, RTOT - 1);
    const ushort* xr = X + (size_t)ar * HID;

#pragma unroll
    for (int kk = 0; kk < 8; kk++) {
        int kst = kk * 32 + kq * 8;
        bf8 af = ldA(xr, kst, sS, sT);
        bf8 b0 = *(const bf8*)&sB[(0 * 16 + r16) * LDB + kst];
        bf8 b1 = *(const bf8*)&sB[(1 * 16 + r16) * LDB + kst];
        bf8 b2 = *(const bf8*)&sB[(2 * 16 + r16) * LDB + kst];
        bf8 b3 = *(const bf8*)&sB[(3 * 16 + r16) * LDB + kst];
        acc[0] = __builtin_amdgcn_mfma_f32_16x16x32_bf16(af, b0, acc[0], 0, 0, 0);
        acc[1] = __builtin_amdgcn_mfma_f32_16x16x32_bf16(af, b1, acc[1], 0, 0, 0);
        acc[2] = __builtin_amdgcn_mfma_f32_16x16x32_bf16(af, b2, acc[2], 0, 0, 0);
        acc[3] = __builtin_amdgcn_mfma_f32_16x16x32_bf16(af, b3, acc[3], 0, 0, 0);
    }

    int rb = bm0 + w * 16;
#pragma unroll
    for (int n = 0; n < 4; n++) {
        int t = bn0 + n * 16 + r16;
        if (t >= 81) continue;
        int gi = t / 9, gj = t - gi * 9;
        int ttr = gj * 9 + gi;
        float bb = b_out[t];
#pragma unroll
        for (int i = 0; i < 4; i++) {
            int r = rb + kq * 4 + i;
            if (r >= RTOT) continue;
            int b = r / PAIRS, p = r - b * PAIRS;
            int2 ij = pairs[p];
            size_t base1 = ((size_t)(b * NB_VAR + ij.x) * NB_VAR + ij.y) * 81;
            size_t base2 = ((size_t)(b * NB_VAR + ij.y) * NB_VAR + ij.x) * 81;
            float v = acc[n][i] + bb;
            out[base1 + t] = v;
            out[base2 + ttr] = v;
        }
    }
}

extern "C" void kernel_launch(void* const* d_in, const int* in_sizes, int n_in,
                              void* d_out, int out_size, void* d_ws, size_t ws_size,
                              hipStream_t stream) {
    const float* x     = (const float*)d_in[0];
    const float* w_in  = (const float*)d_in[1];
    const float* b_in  = (const float*)d_in[2];
    const float* g1    = (const float*)d_in[3];
    const float* beta1 = (const float*)d_in[4];
    const float* w1    = (const float*)d_in[5];
    const float* bias1 = (const float*)d_in[6];
    const float* g2    = (const float*)d_in[7];
    const float* beta2 = (const float*)d_in[8];
    const float* w2    = (const float*)d_in[9];
    const float* bias2 = (const float*)d_in[10];
    const float* fg    = (const float*)d_in[11];
    const float* fbeta = (const float*)d_in[12];
    const float* w_out = (const float*)d_in[13];
    const float* b_out = (const float*)d_in[14];
    float* out = (float*)d_out;

    ushort* buf0 = (ushort*)d_ws;
    ushort* buf1 = buf0 + (size_t)RTOT * HID;
    ushort* buf2 = buf1 + (size_t)RTOT * HID;
    ushort* wbf  = buf2 + (size_t)RTOT * HID;   // 5*65536 elems
    float* stats = (float*)(wbf + 5 * 65536);   // 5 slots x NCPY x 512
    int2*  pairs = (int2*)(stats + 5 * NCPY * 512);
    // wbf layout: w1_0 @0, w1_1 @65536, w2_0 @131072, w2_1 @196608, w_out @262144

    hipMemsetAsync(stats, 0, 5 * NCPY * 512 * sizeof(float), stream);
    k_init<<<405, 256, 0, stream>>>(x, w_in, b_in, w1, w2, w_out, wbf,
                                    pairs, out, buf0, stats + 0 * NCPY * 512);

    k_gemm<<<812, 256, 0, stream>>>(buf0, stats + 0 * NCPY * 512, g1, beta1,
                                    wbf + 0 * 65536, bias1, nullptr, buf1, stats + 1 * NCPY * 512);
    k_gemm<<<812, 256, 0, stream>>>(buf1, stats + 1 * NCPY * 512, g2, beta2,
                                    wbf + 2 * 65536, bias2, buf0, buf2, stats + 2 * NCPY * 512);
    k_gemm<<<812, 256, 0, stream>>>(buf2, stats + 2 * NCPY * 512, g1 + HID, beta1 + HID,
                                    wbf + 1 * 65536, bias1 + HID, nullptr, buf1, stats + 3 * NCPY * 512);
    k_gemm<<<812, 256, 0, stream>>>(buf1, stats + 3 * NCPY * 512, g2 + HID, beta2 + HID,
                                    wbf + 3 * 65536, bias2 + HID, buf2, buf0, stats + 4 * NCPY * 512);
    k_gout<<<406, 256, 0, stream>>>(buf0, stats + 4 * NCPY * 512, fg, fbeta,
                                    wbf + 4 * 65536, b_out, pairs, out);
}